// Round 11
// baseline (294.889 us; speedup 1.0000x reference)
//
#include <hip/hip_runtime.h>
#include <hip/hip_bf16.h>

typedef __attribute__((ext_vector_type(8))) __bf16 bf16x8;
typedef __attribute__((ext_vector_type(4))) float f32x4;

__device__ __forceinline__ unsigned short f2bf(float f) {
  union { float f; unsigned u; } v; v.f = f;
  unsigned r = v.u + 0x7fffu + ((v.u >> 16) & 1u);
  return (unsigned short)(r >> 16);
}

__device__ __forceinline__ void gload_lds16(const void* g, void* s) {
  __builtin_amdgcn_global_load_lds(
      (const __attribute__((address_space(1))) void*)g,
      (__attribute__((address_space(3))) void*)s, 16, 0, 0);
}

// ---- fused prologue launch: weight convert (0-4095) + lrow zero
// ---- (4096-4159, fallback only) + GroupNorm stats (4160-4671).
__global__ __launch_bounds__(256) void convert_w(
    const float* __restrict__ wq, const float* __restrict__ wk,
    const float* __restrict__ wv, const float* __restrict__ wo,
    unsigned short* __restrict__ dst, float* __restrict__ lrow,
    const float* __restrict__ x, float2* __restrict__ partials) {
  const int blk = blockIdx.x;
  const int t = threadIdx.x;
  if (blk >= 4160) {
    const int bgq = blk - 4160;
    const int bg = bgq >> 2, part = bgq & 3;
    const float* xg = x + (size_t)bg * 65536 + part * 1024;
    float s = 0.f, ss = 0.f;
#pragma unroll
    for (int r = 0; r < 16; ++r) {
      const float4 v = *(const float4*)(xg + (size_t)r * 4096 + t * 4);
      s += v.x + v.y + v.z + v.w;
      ss += v.x * v.x + v.y * v.y + v.z * v.z + v.w * v.w;
    }
#pragma unroll
    for (int m = 32; m; m >>= 1) { s += __shfl_xor(s, m); ss += __shfl_xor(ss, m); }
    __shared__ float red[8];
    const int wave = t >> 6, lane = t & 63;
    if (lane == 0) { red[wave] = s; red[wave + 4] = ss; }
    __syncthreads();
    if (t == 0) {
      float2 p;
      p.x = red[0] + red[1] + red[2] + red[3];
      p.y = red[4] + red[5] + red[6] + red[7];
      partials[bgq] = p;
    }
    return;
  }
  if (blk >= 4096) {
    lrow[((blk - 4096) << 8) | t] = 0.f;
    return;
  }
  const int m = blk >> 10;
  const float* src = (m == 0) ? wq : (m == 1) ? wk : (m == 2) ? wv : wo;
  const int idx = ((blk & 1023) << 8) | t;
  dst[m * 262144 + idx] = f2bf(src[idx]);
}

__global__ __launch_bounds__(256) void zero_k(float* __restrict__ p, int n) {
  const int i = blockIdx.x * 256 + threadIdx.x;
  if (i < n) p[i] = 0.f;
}

// ---------------- GroupNorm apply + transpose -> h_t [B,N,C] bf16 ----------
__global__ __launch_bounds__(256) void gn_apply(
    const float* __restrict__ x, const float2* __restrict__ partials,
    const float* __restrict__ gw, const float* __restrict__ gb,
    unsigned short* __restrict__ h_t) {
  const int bg = blockIdx.x >> 3, cc = blockIdx.x & 7;
  const int b = bg >> 5, g = bg & 31;
  const int t = threadIdx.x;
  __shared__ float chs[32];
  __shared__ unsigned short tile[16][520];
  if (t < 16) {
    const float2 p0 = partials[bg * 4 + 0], p1 = partials[bg * 4 + 1];
    const float2 p2 = partials[bg * 4 + 2], p3 = partials[bg * 4 + 3];
    const float S = p0.x + p1.x + p2.x + p3.x;
    const float SS = p0.y + p1.y + p2.y + p3.y;
    const float mu = S * (1.f / 65536.f);
    const float rstd = rsqrtf(SS * (1.f / 65536.f) - mu * mu + 1e-5f);
    const float sc = gw[g * 16 + t] * rstd;
    chs[t] = sc;
    chs[16 + t] = gb[g * 16 + t] - mu * sc;
  }
  __syncthreads();
  const float* xg = x + (size_t)bg * 65536 + cc * 512;
#pragma unroll
  for (int rr = 0; rr < 8; ++rr) {
    const int r = rr * 2 + (t >> 7), i = (t & 127) * 4;
    const float4 v = *(const float4*)(xg + (size_t)r * 4096 + i);
    const float sc = chs[r], sh = chs[16 + r];
    ushort4 o;
    o.x = f2bf(v.x * sc + sh); o.y = f2bf(v.y * sc + sh);
    o.z = f2bf(v.z * sc + sh); o.w = f2bf(v.w * sc + sh);
    *(ushort4*)&tile[r][i] = o;
  }
  __syncthreads();
  unsigned short* outp = h_t + ((size_t)b * 4096 + cc * 512) * 512 + g * 16;
#pragma unroll
  for (int rep = 0; rep < 4; ++rep) {
    const int task = rep * 256 + t;
    const int nl = task >> 1, half = (task & 1) * 8;
    ushort4 o0, o1;
    o0.x = tile[half + 0][nl]; o0.y = tile[half + 1][nl];
    o0.z = tile[half + 2][nl]; o0.w = tile[half + 3][nl];
    o1.x = tile[half + 4][nl]; o1.y = tile[half + 5][nl];
    o1.z = tile[half + 6][nl]; o1.w = tile[half + 7][nl];
    *(ushort4*)(outp + (size_t)nl * 512 + half) = o0;
    *(ushort4*)(outp + (size_t)nl * 512 + half + 4) = o1;
  }
}

// ------- reduce 4 fp32 split-K partials, normalize by l[row] -> bf16 --------
__global__ __launch_bounds__(256) void reduce4_k(
    const float* __restrict__ part, const float* __restrict__ l,
    unsigned short* __restrict__ dst) {
  const size_t i = ((size_t)blockIdx.x * 256 + threadIdx.x) * 4;
  f32x4 s0 = *(const f32x4*)(part + i);
  f32x4 s1 = *(const f32x4*)(part + 2097152 + i);
  f32x4 s2 = *(const f32x4*)(part + 4194304 + i);
  f32x4 s3 = *(const f32x4*)(part + 6291456 + i);
  f32x4 s = (s0 + s1) + (s2 + s3);
  const float inv = 1.f / l[i >> 9];
  ushort4 o;
  o.x = f2bf(s[0] * inv); o.y = f2bf(s[1] * inv);
  o.z = f2bf(s[2] * inv); o.w = f2bf(s[3] * inv);
  *(ushort4*)(dst + i) = o;
}

// ---- fused QKV GEMM: 256 threads, 128x128 tiles, grid (12,32,4) -----------
__global__ __launch_bounds__(256) void gemm_qkv(
    const unsigned short* __restrict__ H, const unsigned short* __restrict__ W,
    unsigned short* __restrict__ q_t, unsigned short* __restrict__ k_t,
    unsigned short* __restrict__ v_ct,
    const float* __restrict__ bq, const float* __restrict__ bk,
    const float* __restrict__ bv, float qscale) {
  __shared__ __align__(16) char smem[49152];  // 3 bufs x (A 8KB + B 8KB)
  const int tid = threadIdx.x;
  const int wave = tid >> 6, lane = tid & 63;
  const int l15 = lane & 15, l4 = lane >> 4;
  const int wm = wave >> 1, wn = wave & 1;

  const int bx = blockIdx.x, by = blockIdx.y, bz = blockIdx.z;
  const int mode = bx >> 2;          // 0=q 1=k 2=v
  const int colv = (bx & 3) << 7;
  const int row0 = by << 7;
  const unsigned short* A = H + (size_t)bz * 2097152;
  const unsigned short* Bt = W + (size_t)bx * 65536;

  const int ar = tid >> 2;
  const int akc = (tid & 3) ^ ((tid >> 3) & 3);  // row bits 1-2

  auto stage = [&](int kt, int bi) {
    const int kb = kt << 5;
    char* sAl = smem + bi * 16384 + wave * 1024;
    char* sBl = sAl + 8192;
    const unsigned short* gA = A + (size_t)(row0 + ar) * 512 + kb + akc * 8;
    const unsigned short* gB = Bt + (size_t)ar * 512 + kb + akc * 8;
    gload_lds16(gA, sAl);
    gload_lds16(gB, sBl);
    gload_lds16(gA + (size_t)64 * 512, sAl + 4096);
    gload_lds16(gB + (size_t)64 * 512, sBl + 4096);
  };

  f32x4 acc[4][4];
#pragma unroll
  for (int r = 0; r < 4; ++r)
#pragma unroll
    for (int c = 0; c < 4; ++c) acc[r][c] = (f32x4)0.f;

  const int xsw = (l4 ^ ((l15 >> 1) & 3)) << 4;

  auto compute = [&](int bi) {
    const char* pa = smem + bi * 16384 + (wm * 64 + l15) * 64 + xsw;
    const char* pb = smem + bi * 16384 + 8192 + (wn * 64 + l15) * 64 + xsw;
    bf16x8 af[4], bfr[4];
#pragma unroll
    for (int r = 0; r < 4; ++r) af[r] = *(const bf16x8*)(pa + r * 1024);
#pragma unroll
    for (int c = 0; c < 4; ++c) bfr[c] = *(const bf16x8*)(pb + c * 1024);
#pragma unroll
    for (int r = 0; r < 4; ++r)
#pragma unroll
      for (int c = 0; c < 4; ++c)
        acc[r][c] = __builtin_amdgcn_mfma_f32_16x16x32_bf16(af[r], bfr[c], acc[r][c], 0, 0, 0);
  };

  stage(0, 0);
  stage(1, 1);
  int bi = 0;
  for (int kt = 0; kt < 15; ++kt) {
    asm volatile("s_waitcnt vmcnt(4)" ::: "memory");
    __builtin_amdgcn_s_barrier();
    __builtin_amdgcn_sched_barrier(0);
    if (kt + 2 < 16) stage(kt + 2, (kt + 2) % 3);
    compute(bi);
    bi = (bi == 2) ? 0 : bi + 1;
  }
  asm volatile("s_waitcnt vmcnt(0)" ::: "memory");
  __builtin_amdgcn_s_barrier();
  __builtin_amdgcn_sched_barrier(0);
  compute(bi);

  const float* bias = (mode == 0) ? bq : (mode == 1) ? bk : bv;
  const float scale = (mode == 0) ? qscale : 1.0f;
  __syncthreads();
  if (mode < 2) {
    unsigned short* outp = ((mode == 0) ? q_t : k_t) + (size_t)bz * 2097152;
    unsigned short* tile = (unsigned short*)smem;
#pragma unroll
    for (int c = 0; c < 4; ++c) {
      const int coll = wn * 64 + c * 16 + l15;
      const float badd = bias[colv + coll];
#pragma unroll
      for (int r = 0; r < 4; ++r) {
        const int rowl = wm * 64 + r * 16 + l4 * 4;
#pragma unroll
        for (int j = 0; j < 4; ++j)
          tile[(rowl + j) * 136 + coll] = f2bf((acc[r][c][j] + badd) * scale);
      }
    }
    __syncthreads();
#pragma unroll
    for (int it = 0; it < 8; ++it) {
      const int idx = it * 256 + tid;
      const int rw = idx >> 4, ch = (idx & 15) * 8;
      const uint4 vv = *(const uint4*)&tile[rw * 136 + ch];
      *(uint4*)(outp + (size_t)(row0 + rw) * 512 + colv + ch) = vv;
    }
  } else {
    unsigned short* outp = v_ct + (size_t)bz * 2097152;
    unsigned short* tile = (unsigned short*)smem;
#pragma unroll
    for (int c = 0; c < 4; ++c) {
      const int coll = wn * 64 + c * 16 + l15;
      const float badd = bias[colv + coll];
#pragma unroll
      for (int r = 0; r < 4; ++r) {
        const int rowl = wm * 64 + r * 16 + l4 * 4;
#pragma unroll
        for (int j = 0; j < 4; ++j)
          tile[(rowl + j) * 132 + coll] = f2bf(acc[r][c][j] + badd);
      }
    }
    __syncthreads();
#pragma unroll 8
    for (int it = 0; it < 64; ++it) {
      const int idx = it * 256 + tid;
      const int cl = idx >> 7, il = idx & 127;
      outp[(size_t)(colv + cl) * 4096 + row0 + il] = tile[il * 132 + cl];
    }
  }
}

// ---- FUSED ATTENTION: out[b,r,c] = sum_j exp(q.k)*v / sum_j exp(q.k) -----
// 256 blocks (1/CU), 512 threads, 155.9KB LDS.  Block: 64 Q-rows x 512 ch,
// j-loop 16 tiles of 256.  Per j-tile: QK^T (8 kc-chunks of K=64; Q+K staged
// per chunk, triple-buffered 40KB bufs, counted vmcnt(5) - continuous 128-
// step pipeline across j-tiles) -> exp -> S_lds (XOR-swizzled 512B rows) +
// register rowsum partials -> PV (A from S_lds, B direct global from L2-
// resident v_ct).  XCD map: 32 blocks/XCD all same batch -> v_ct[b] (4MB)
// pinned per XCD L2.  MFMA chains match gemm_s256 (k-asc) / gemm_pv (j-asc).
// R10 bug (half-tile output store) fixed: 8 its x 8-short chunks = full
// 64x512 coverage.
__global__ __launch_bounds__(512, 2) void attn_fused(
    const unsigned short* __restrict__ Q, const unsigned short* __restrict__ K,
    const unsigned short* __restrict__ V, unsigned short* __restrict__ O) {
  __shared__ __align__(16) char smem[155904];
  // [0,122880): 3 x 40960 staging bufs (Q 8KB + K 32KB each)
  // [122880,155648): S_lds 64 rows x 512B (256 j bf16, slot^=(row&7))
  // [155648,155904): rowsum[64] f32
  const int tid = threadIdx.x;
  const int wave = tid >> 6, lane = tid & 63;
  const int l15 = lane & 15, l4 = lane >> 4;
  const int wm = wave >> 2, wn = wave & 3;  // QK: 2(rows of 32) x 4(j of 64)

  const int bid = blockIdx.x;
  const int xcd = bid & 7;
  const int bz = xcd >> 1;                       // 2 XCDs per batch
  const int rp = (bid >> 3) | ((xcd & 1) << 5);  // 64 row-panels per batch
  const int row0 = rp << 6;

  const unsigned short* Qb = Q + (size_t)bz * 2097152;
  const unsigned short* Kb = K + (size_t)bz * 2097152;
  const unsigned short* Vb = V + (size_t)bz * 2097152;
  unsigned short* Ob = O + (size_t)bz * 2097152;

  float* rowsum = (float*)(smem + 155648);
  if (tid < 64) rowsum[tid] = 0.f;

  const int sr = tid >> 3;               // staging row within 64-row pass
  const int sl = (tid & 7) ^ (sr & 7);   // pre-swizzled 16B chunk (XOR-8)

  // stage global step g (jt = g>>3, kc = g&7): Q 1 pass + K 4 passes
  auto stage = [&](int g, int dbuf) {
    const int jt = g >> 3, kc = g & 7;
    char* base = smem + dbuf * 40960;
    gload_lds16(Qb + (size_t)(row0 + sr) * 512 + kc * 64 + sl * 8,
                base + wave * 1024);
#pragma unroll
    for (int p = 0; p < 4; ++p)
      gload_lds16(Kb + (size_t)(jt * 256 + p * 64 + sr) * 512 + kc * 64 + sl * 8,
                  base + 8192 + p * 8192 + wave * 1024);
  };

  f32x4 pvacc[4][4];  // rows rf*16+l4*4+reg  x  cols wave*64+cf*16+l15
#pragma unroll
  for (int r = 0; r < 4; ++r)
#pragma unroll
    for (int c = 0; c < 4; ++c) pvacc[r][c] = (f32x4)0.f;
  float sp[2][4];  // rowsum partials [rf][reg] (this wave's j-slices)
#pragma unroll
  for (int r = 0; r < 2; ++r)
#pragma unroll
    for (int c = 0; c < 4; ++c) sp[r][c] = 0.f;

  stage(0, 0);
  stage(1, 1);
  int bi = 0;

#pragma unroll 1
  for (int jt = 0; jt < 16; ++jt) {
    // ---- QK^T phase: S[64 x 256] over K=512 in 8 chunks of 64 ----
    f32x4 sacc[2][4];  // [rf rows16][jf j16]
#pragma unroll
    for (int r = 0; r < 2; ++r)
#pragma unroll
      for (int c = 0; c < 4; ++c) sacc[r][c] = (f32x4)0.f;
#pragma unroll
    for (int kc = 0; kc < 8; ++kc) {
      const int g = jt * 8 + kc;
      if (g + 1 < 128) asm volatile("s_waitcnt vmcnt(5)" ::: "memory");
      else             asm volatile("s_waitcnt vmcnt(0)" ::: "memory");
      __builtin_amdgcn_s_barrier();
      __builtin_amdgcn_sched_barrier(0);
      if (g + 2 < 128) stage(g + 2, (bi + 2) % 3);
      const char* bufQ = smem + bi * 40960;
      const char* bufK = bufQ + 8192;
#pragma unroll
      for (int ks = 0; ks < 2; ++ks) {
        bf16x8 qf[2], kf[4];
#pragma unroll
        for (int rf = 0; rf < 2; ++rf) {
          const int row = wm * 32 + rf * 16 + l15;
          qf[rf] = *(const bf16x8*)(bufQ + row * 128 + (((ks * 4 + l4) ^ (row & 7)) << 4));
        }
#pragma unroll
        for (int jf = 0; jf < 4; ++jf) {
          const int jr = wn * 64 + jf * 16 + l15;
          kf[jf] = *(const bf16x8*)(bufK + jr * 128 + (((ks * 4 + l4) ^ (jr & 7)) << 4));
        }
#pragma unroll
        for (int rf = 0; rf < 2; ++rf)
#pragma unroll
          for (int jf = 0; jf < 4; ++jf)
            sacc[rf][jf] = __builtin_amdgcn_mfma_f32_16x16x32_bf16(
                qf[rf], kf[jf], sacc[rf][jf], 0, 0, 0);
      }
      bi = (bi == 2) ? 0 : bi + 1;
    }

    // ---- exp -> S_lds (bf16) + rowsum partials ----
    char* Sb = smem + 122880;
#pragma unroll
    for (int rf = 0; rf < 2; ++rf)
#pragma unroll
      for (int jf = 0; jf < 4; ++jf)
#pragma unroll
        for (int reg = 0; reg < 4; ++reg) {
          const int row = wm * 32 + rf * 16 + l4 * 4 + reg;
          const int j = wn * 64 + jf * 16 + l15;
          const float e = __expf(sacc[rf][jf][reg]);
          const unsigned short us = f2bf(e);
          const int slot = (j >> 3) ^ (row & 7);
          *(unsigned short*)(Sb + row * 512 + (slot << 4) + (l15 & 7) * 2) = us;
          union { unsigned u; float f; } w; w.u = (unsigned)us << 16;
          sp[rf][reg] += w.f;
        }
    asm volatile("s_waitcnt lgkmcnt(0)" ::: "memory");
    __builtin_amdgcn_s_barrier();

    // ---- PV phase: pvacc += S[64x256] @ V[ch, j-tile]^T ----
#pragma unroll
    for (int ks = 0; ks < 8; ++ks) {
      bf16x8 af[4], bfr[4];
#pragma unroll
      for (int rf = 0; rf < 4; ++rf) {
        const int row = rf * 16 + l15;
        af[rf] = *(const bf16x8*)(Sb + row * 512 + (((ks * 4 + l4) ^ (row & 7)) << 4));
      }
#pragma unroll
      for (int cf = 0; cf < 4; ++cf) {
        const int c = wave * 64 + cf * 16 + l15;
        bfr[cf] = *(const bf16x8*)(Vb + (size_t)c * 4096 + jt * 256 + ks * 32 + l4 * 8);
      }
#pragma unroll
      for (int rf = 0; rf < 4; ++rf)
#pragma unroll
        for (int cf = 0; cf < 4; ++cf)
          pvacc[rf][cf] = __builtin_amdgcn_mfma_f32_16x16x32_bf16(
              af[rf], bfr[cf], pvacc[rf][cf], 0, 0, 0);
    }
    __builtin_amdgcn_s_barrier();  // seal S_lds before next jt's writes
  }

  // ---- rowsum: reduce partials over l15, combine waves via LDS atomics ----
#pragma unroll
  for (int rf = 0; rf < 2; ++rf)
#pragma unroll
    for (int reg = 0; reg < 4; ++reg) {
      float s = sp[rf][reg];
      s += __shfl_xor(s, 1); s += __shfl_xor(s, 2);
      s += __shfl_xor(s, 4); s += __shfl_xor(s, 8);
      if (l15 == 0) atomicAdd(&rowsum[wm * 32 + rf * 16 + l4 * 4 + reg], s);
    }
  __syncthreads();

  // ---- epilogue: normalize -> bf16 -> [64][520] tile -> coalesced stores --
  unsigned short* tile = (unsigned short*)smem;  // aliases dead staging bufs
#pragma unroll
  for (int rf = 0; rf < 4; ++rf)
#pragma unroll
    for (int cf = 0; cf < 4; ++cf)
#pragma unroll
      for (int reg = 0; reg < 4; ++reg) {
        const int row = rf * 16 + l4 * 4 + reg;
        const int c = wave * 64 + cf * 16 + l15;
        tile[row * 520 + c] = f2bf(pvacc[rf][cf][reg] * (1.0f / rowsum[row]));
      }
  __syncthreads();
#pragma unroll
  for (int it = 0; it < 8; ++it) {
    const int idx = it * 512 + tid;  // 64 rows x 64 chunks of 8 shorts (FULL)
    const int rw = idx >> 6, ch = (idx & 63) * 8;
    const uint4 vv = *(const uint4*)&tile[rw * 520 + ch];
    *(uint4*)(Ob + (size_t)(row0 + rw) * 512 + ch) = vv;
  }
}

// ---- S-kernel (fallback path only): 256x128 tile, 72KB LDS, 2 blk/CU ----
__global__ __launch_bounds__(512, 4) void gemm_s256(
    const unsigned short* __restrict__ A, const unsigned short* __restrict__ Bt,
    unsigned short* __restrict__ Out, float* __restrict__ lsum) {
  __shared__ __align__(16) char smem[73728];
  const int tid = threadIdx.x;
  const int wave = tid >> 6, lane = tid & 63;
  const int l15 = lane & 15, l4 = lane >> 4;
  const int wm = wave >> 1, wn = wave & 1;

  const int bz = blockIdx.z;
  A += (size_t)bz * 2097152;
  Bt += (size_t)bz * 2097152;
  Out += (size_t)bz * 16777216;
  lsum += (size_t)bz * 4096;

  const int id = blockIdx.y * 32 + blockIdx.x;
  const int xcd = id & 7, j = id >> 3;
  const int by = ((xcd >> 1) << 2) + (j >> 4);
  const int bx = ((xcd & 1) << 4) + (j & 15);
  const int row0 = by << 8, col0 = bx << 7;

  const int ar = tid >> 2;
  const int akc = (tid & 3) ^ ((tid >> 3) & 3);

  auto stage = [&](int kt, int bi) {
    const int kb = kt << 5;
    char* base = smem + bi * 24576;
    const unsigned short* gA = A + (size_t)(row0 + ar) * 512 + kb + akc * 8;
    const unsigned short* gB = Bt + (size_t)(col0 + ar) * 512 + kb + akc * 8;
    gload_lds16(gA, base + wave * 1024);
    gload_lds16(gA + (size_t)128 * 512, base + 8192 + wave * 1024);
    gload_lds16(gB, base + 16384 + wave * 1024);
  };

  f32x4 acc[4][4];
#pragma unroll
  for (int r = 0; r < 4; ++r)
#pragma unroll
    for (int c = 0; c < 4; ++c) acc[r][c] = (f32x4)0.f;

  const int xsw = (l4 ^ ((l15 >> 1) & 3)) << 4;

  auto compute = [&](int bi) {
    const char* pa = smem + bi * 24576 + (wm * 64 + l15) * 64 + xsw;
    const char* pb = smem + bi * 24576 + 16384 + (wn * 64 + l15) * 64 + xsw;
    bf16x8 af[4], bfr[4];
#pragma unroll
    for (int r = 0; r < 4; ++r) af[r] = *(const bf16x8*)(pa + r * 1024);
#pragma unroll
    for (int c = 0; c < 4; ++c) bfr[c] = *(const bf16x8*)(pb + c * 1024);
#pragma unroll
    for (int r = 0; r < 4; ++r)
#pragma unroll
      for (int c = 0; c < 4; ++c)
        acc[r][c] = __builtin_amdgcn_mfma_f32_16x16x32_bf16(af[r], bfr[c], acc[r][c], 0, 0, 0);
  };

  stage(0, 0);
  stage(1, 1);
  int bi = 0;
  for (int kt = 0; kt < 15; ++kt) {
    asm volatile("s_waitcnt vmcnt(3)" ::: "memory");
    __builtin_amdgcn_s_barrier();
    __builtin_amdgcn_sched_barrier(0);
    if (kt + 2 < 16) stage(kt + 2, (kt + 2) % 3);
    compute(bi);
    bi = (bi == 2) ? 0 : bi + 1;
  }
  asm volatile("s_waitcnt vmcnt(0)" ::: "memory");
  __builtin_amdgcn_s_barrier();
  __builtin_amdgcn_sched_barrier(0);
  compute(bi);

  __syncthreads();
  unsigned short* tile = (unsigned short*)smem;  // [256][136]
#pragma unroll
  for (int c = 0; c < 4; ++c) {
    const int coll = wn * 64 + c * 16 + l15;
#pragma unroll
    for (int r = 0; r < 4; ++r) {
      const int rowl = wm * 64 + r * 16 + l4 * 4;
#pragma unroll
      for (int j2 = 0; j2 < 4; ++j2)
        tile[(rowl + j2) * 136 + coll] = f2bf(__expf(acc[r][c][j2]));
    }
  }
  __syncthreads();
#pragma unroll
  for (int it = 0; it < 8; ++it) {
    const int idx = it * 512 + tid;
    const int rw = idx >> 4, ch = (idx & 15) * 8;
    const uint4 vv = *(const uint4*)&tile[rw * 136 + ch];
    *(uint4*)(Out + (size_t)(row0 + rw) * 4096 + col0 + ch) = vv;
    const unsigned* uu = (const unsigned*)&vv;
    float s = 0.f;
#pragma unroll
    for (int q = 0; q < 4; ++q) {
      union { unsigned u; float f; } w;
      w.u = uu[q] << 16; s += w.f;
      w.u = uu[q] & 0xffff0000u; s += w.f;
    }
    s += __shfl_xor(s, 1); s += __shfl_xor(s, 2);
    s += __shfl_xor(s, 4); s += __shfl_xor(s, 8);
    if ((lane & 15) == 0) atomicAdd(&lsum[row0 + rw], s);
  }
}

// ---------------- GEMM: C[M,N] = A[M,K] * Bt[N,K]^T  (bf16 in, fp32 acc) ----
template <bool OUT_BF16, int BIAS_MODE, bool RESID, bool TRANS_OUT, int SWZ,
          bool COAL>
__global__ __launch_bounds__(256) void gemm_bt(
    const unsigned short* __restrict__ A, long long sA, int lda,
    const unsigned short* __restrict__ Bt, long long sB, int ldb,
    void* __restrict__ OutV, long long sO, int ldo,
    const float* __restrict__ bias,
    const float* __restrict__ resid, long long sR,
    int K, float scale) {
  __shared__ __align__(16) char smem[49152];
  const int tid = threadIdx.x;
  const int wave = tid >> 6, lane = tid & 63;
  const int l15 = lane & 15, l4 = lane >> 4;
  const int wm = wave >> 1, wn = wave & 1;

  int bx = blockIdx.x, by = blockIdx.y, bz = blockIdx.z;
  if constexpr (SWZ == 1) {
    const int id = by * 32 + bx;
    const int xcd = id & 7, j = id >> 3;
    by = ((xcd >> 1) << 3) + (j >> 4);
    bx = ((xcd & 1) << 4) + (j & 15);
  } else if constexpr (SWZ == 2) {
    const int L = bx + ((by + (bz << 5)) << 2);
    const int xcd = L & 7, j = L >> 3;
    const int pair = xcd * 16 + (j >> 2);
    bx = j & 3;
    by = pair & 31;
    bz = pair >> 5;
  }
  const int row0 = by << 7, col0 = bx << 7;
  A += (size_t)bz * sA;
  Bt += (size_t)bz * sB;
  if (RESID) resid += (size_t)bz * sR;
  if constexpr (BIAS_MODE == 3) bias += (size_t)bz * sR;
  char* outB = (char*)OutV + (size_t)bz * sO * (OUT_BF16 ? 2 : 4);

  const int ar = tid >> 2;
  const int akc = (tid & 3) ^ ((tid >> 3) & 3);

  auto stage = [&](int kt, int bi) {
    const int kb = kt << 5;
    char* sAl = smem + bi * 16384 + wave * 1024;
    char* sBl = sAl + 8192;
    const unsigned short* gA = A + (size_t)(row0 + ar) * lda + kb + akc * 8;
    const unsigned short* gB = Bt + (size_t)(col0 + ar) * ldb + kb + akc * 8;
    gload_lds16(gA, sAl);
    gload_lds16(gB, sBl);
    gload_lds16(gA + (size_t)64 * lda, sAl + 4096);
    gload_lds16(gB + (size_t)64 * ldb, sBl + 4096);
  };

  f32x4 acc[4][4];
#pragma unroll
  for (int r = 0; r < 4; ++r)
#pragma unroll
    for (int c = 0; c < 4; ++c) acc[r][c] = (f32x4)0.f;

  const int nk = K >> 5;
  const int xsw = (l4 ^ ((l15 >> 1) & 3)) << 4;

  auto compute = [&](int bi) {
    const char* pa = smem + bi * 16384 + (wm * 64 + l15) * 64 + xsw;
    const char* pb = smem + bi * 16384 + 8192 + (wn * 64 + l15) * 64 + xsw;
    bf16x8 af[4], bfr[4];
#pragma unroll
    for (int r = 0; r < 4; ++r) af[r] = *(const bf16x8*)(pa + r * 1024);
#pragma unroll
    for (int c = 0; c < 4; ++c) bfr[c] = *(const bf16x8*)(pb + c * 1024);
#pragma unroll
    for (int r = 0; r < 4; ++r)
#pragma unroll
      for (int c = 0; c < 4; ++c)
        acc[r][c] = __builtin_amdgcn_mfma_f32_16x16x32_bf16(af[r], bfr[c], acc[r][c], 0, 0, 0);
  };

  stage(0, 0);
  stage(1, 1);
  int bi = 0;
  for (int kt = 0; kt < nk - 1; ++kt) {
    asm volatile("s_waitcnt vmcnt(4)" ::: "memory");
    __builtin_amdgcn_s_barrier();
    __builtin_amdgcn_sched_barrier(0);
    if (kt + 2 < nk) stage(kt + 2, (kt + 2) % 3);
    compute(bi);
    bi = (bi == 2) ? 0 : bi + 1;
  }
  asm volatile("s_waitcnt vmcnt(0)" ::: "memory");
  __builtin_amdgcn_s_barrier();
  __builtin_amdgcn_sched_barrier(0);
  compute(bi);

  if constexpr (COAL && !TRANS_OUT) {
    __syncthreads();
    if constexpr (OUT_BF16) {
      unsigned short* tile = (unsigned short*)smem;  // [128][136]
#pragma unroll
      for (int c = 0; c < 4; ++c) {
        const int coll = wn * 64 + c * 16 + l15;
        float badd = 0.f;
        if constexpr (BIAS_MODE == 1) badd = bias[col0 + coll];
#pragma unroll
        for (int r = 0; r < 4; ++r) {
          const int rowl = wm * 64 + r * 16 + l4 * 4;
#pragma unroll
          for (int j = 0; j < 4; ++j) {
            float v;
            if constexpr (BIAS_MODE == 3)
              v = acc[r][c][j] * (1.0f / bias[row0 + rowl + j]);
            else
              v = (acc[r][c][j] + badd) * scale;
            tile[(rowl + j) * 136 + coll] = f2bf(v);
          }
        }
      }
      __syncthreads();
      unsigned short* outp = (unsigned short*)outB;
#pragma unroll
      for (int it = 0; it < 8; ++it) {
        const int idx = it * 256 + tid;
        const int rw = idx >> 4, ch = (idx & 15) * 8;
        const uint4 vv = *(const uint4*)&tile[rw * 136 + ch];
        *(uint4*)(outp + (size_t)(row0 + rw) * ldo + col0 + ch) = vv;
      }
    } else {
      float* tile = (float*)smem;  // [64][132]
#pragma unroll
      for (int p = 0; p < 2; ++p) {
        if (wm == p) {
#pragma unroll
          for (int c = 0; c < 4; ++c) {
            const int coll = wn * 64 + c * 16 + l15;
            float badd = 0.f;
            if constexpr (BIAS_MODE == 1) badd = bias[col0 + coll];
#pragma unroll
            for (int r = 0; r < 4; ++r) {
              const int rowl = r * 16 + l4 * 4;
#pragma unroll
              for (int j = 0; j < 4; ++j) {
                float v = acc[r][c][j] + badd;
                if constexpr (BIAS_MODE == 2) v += bias[row0 + p * 64 + rowl + j];
                tile[(rowl + j) * 132 + coll] = v * scale;
              }
            }
          }
        }
        __syncthreads();
        float* outp = (float*)outB;
#pragma unroll
        for (int it = 0; it < 8; ++it) {
          const int idx = it * 256 + tid;
          const int rw = idx >> 5, ch = (idx & 31) * 4;
          const int rowg = row0 + p * 64 + rw;
          f32x4 v = *(const f32x4*)&tile[rw * 132 + ch];
          if constexpr (RESID) {
            const float* rp = resid + (size_t)rowg * ldo + col0 + ch;
            v[0] += rp[0]; v[1] += rp[1]; v[2] += rp[2]; v[3] += rp[3];
          }
          *(f32x4*)(outp + (size_t)rowg * ldo + col0 + ch) = v;
        }
        __syncthreads();
      }
    }
  } else if constexpr (!TRANS_OUT) {
#pragma unroll
    for (int c = 0; c < 4; ++c) {
      const int colg = col0 + wn * 64 + c * 16 + l15;
      float badd = 0.f;
      if constexpr (BIAS_MODE == 1) badd = bias[colg];
#pragma unroll
      for (int r = 0; r < 4; ++r) {
        const int rowg = row0 + wm * 64 + r * 16 + l4 * 4;
#pragma unroll
        for (int j = 0; j < 4; ++j) {
          float v = acc[r][c][j] + badd;
          if constexpr (BIAS_MODE == 2) v += bias[rowg + j];
          v *= scale;
          if constexpr (RESID) v += resid[(size_t)(rowg + j) * ldo + colg];
          if constexpr (OUT_BF16)
            ((unsigned short*)outB)[(size_t)(rowg + j) * ldo + colg] = f2bf(v);
          else
            ((float*)outB)[(size_t)(rowg + j) * ldo + colg] = v;
        }
      }
    }
  } else {
    __syncthreads();
    unsigned short* tile = (unsigned short*)smem;  // [128][132]
#pragma unroll
    for (int c = 0; c < 4; ++c) {
      const int coll = wn * 64 + c * 16 + l15;
      float badd = 0.f;
      if constexpr (BIAS_MODE == 1) badd = bias[col0 + coll];
#pragma unroll
      for (int r = 0; r < 4; ++r) {
        const int rowl = wm * 64 + r * 16 + l4 * 4;
#pragma unroll
        for (int j = 0; j < 4; ++j)
          tile[(rowl + j) * 132 + coll] = f2bf((acc[r][c][j] + badd) * scale);
      }
    }
    __syncthreads();
    unsigned short* outp = (unsigned short*)outB;
#pragma unroll 8
    for (int it = 0; it < 64; ++it) {
      const int idx = it * 256 + tid;
      const int cl = idx >> 7, il = idx & 127;
      outp[(size_t)(col0 + cl) * ldo + row0 + il] = tile[il * 132 + cl];
    }
  }
}

extern "C" void kernel_launch(void* const* d_in, const int* in_sizes, int n_in,
                              void* d_out, int out_size, void* d_ws, size_t ws_size,
                              hipStream_t stream) {
  const float* x   = (const float*)d_in[0];
  const float* gnw = (const float*)d_in[1];
  const float* gnb = (const float*)d_in[2];
  const float* wq  = (const float*)d_in[3];
  const float* bq  = (const float*)d_in[4];
  const float* wk  = (const float*)d_in[5];
  const float* bk  = (const float*)d_in[6];
  const float* wv  = (const float*)d_in[7];
  const float* bv  = (const float*)d_in[8];
  const float* wo  = (const float*)d_in[9];
  const float* bo  = (const float*)d_in[10];
  float* out = (float*)d_out;
  char* ws = (char*)d_ws;

  const size_t MB = 1u << 20;
  float2*         gnp  = (float2*)ws;                          // 4 KB partials
  float*          lrow = (float*)(ws + 64 * 1024);             // 64 KB (fallback)
  unsigned short* wbf  = (unsigned short*)(ws + 1 * MB);       // 2 MB
  unsigned short* h_t  = (unsigned short*)(ws + 3 * MB);       // 16 MB [B,N,C]
  unsigned short* q_t  = (unsigned short*)(ws + 19 * MB);      // 16 MB
  unsigned short* k_t  = (unsigned short*)(ws + 35 * MB);      // 16 MB
  unsigned short* v_ct = (unsigned short*)(ws + 51 * MB);      // 16 MB [B,C,N]
  unsigned short* h2_t = (unsigned short*)(ws + 67 * MB);      // 16 MB
  unsigned short* Pbuf = (unsigned short*)(ws + 83 * MB);      // fallback only
  float*          part = (float*)(ws + 115 * MB);              // fallback only

  const long long BS = 2097152;    // 4096*512 per-batch stride
  const float qscale = 0.044194173824159216f;  // 512^-0.5
  const bool batched = ws_size >= 212 * MB;

  // weight convert + lrow zero + gn_stats in ONE launch (all input-only)
  convert_w<<<dim3(4672), dim3(256), 0, stream>>>(wq, wk, wv, wo, wbf, lrow, x, gnp);
  gn_apply<<<dim3(1024), dim3(256), 0, stream>>>(x, gnp, gnw, gnb, h_t);

  // fused q/k/v: one 256-thread launch, deep grid (1536 blocks)
  gemm_qkv<<<dim3(12, 32, 4), dim3(256), 0, stream>>>(
      h_t, wbf, q_t, k_t, v_ct, bq, bk, bv, qscale);

  if (batched) {
    // fused attention: no P buffer, no lrow, one launch
    attn_fused<<<dim3(256), dim3(512), 0, stream>>>(q_t, k_t, v_ct, h2_t);
  } else {
    for (int b = 0; b < 4; ++b) {
      zero_k<<<dim3(16), dim3(256), 0, stream>>>(lrow, 4096);
      gemm_s256<<<dim3(32, 16, 1), dim3(512), 0, stream>>>(
          q_t + (size_t)b * BS, k_t + (size_t)b * BS, Pbuf, lrow);
      gemm_bt<false, 0, false, false, 0, true><<<dim3(4, 32, 4), 256, 0, stream>>>(
          Pbuf, 1024, 4096, v_ct + (size_t)b * BS, 1024, 4096,
          part, 2097152, 512, nullptr, nullptr, 0, 1024, 1.0f);
      reduce4_k<<<dim3(2048), dim3(256), 0, stream>>>(part, lrow, h2_t + (size_t)b * BS);
    }
  }

  // out[b,o,i] = x[b,o,i] + bo[o] + sum_c wo[o,c] h2[b,i,c]
  gemm_bt<false, 2, true, false, 0, true><<<dim3(32, 4, 4), 256, 0, stream>>>(
      wbf + 786432, 0, 512, h2_t, BS, 512, out, BS, 4096, bo, x, BS, 512, 1.0f);
}

// Round 12
// 247.868 us; speedup vs baseline: 1.1897x; 1.1897x over previous
//
#include <hip/hip_runtime.h>
#include <hip/hip_bf16.h>

typedef __attribute__((ext_vector_type(8))) __bf16 bf16x8;
typedef __attribute__((ext_vector_type(4))) float f32x4;

__device__ __forceinline__ unsigned short f2bf(float f) {
  union { float f; unsigned u; } v; v.f = f;
  unsigned r = v.u + 0x7fffu + ((v.u >> 16) & 1u);
  return (unsigned short)(r >> 16);
}

__device__ __forceinline__ void gload_lds16(const void* g, void* s) {
  __builtin_amdgcn_global_load_lds(
      (const __attribute__((address_space(1))) void*)g,
      (__attribute__((address_space(3))) void*)s, 16, 0, 0);
}

// ---- fused prologue launch: weight convert (0-4095) + lrow zero
// ---- (4096-4159) + GroupNorm stats (4160-4671).  All input-only -> one
// ---- launch, one boundary fewer.
__global__ __launch_bounds__(256) void convert_w(
    const float* __restrict__ wq, const float* __restrict__ wk,
    const float* __restrict__ wv, const float* __restrict__ wo,
    unsigned short* __restrict__ dst, float* __restrict__ lrow,
    const float* __restrict__ x, float2* __restrict__ partials) {
  const int blk = blockIdx.x;
  const int t = threadIdx.x;
  if (blk >= 4160) {
    // gn_stats: partial sums per (b,g,quarter)
    const int bgq = blk - 4160;
    const int bg = bgq >> 2, part = bgq & 3;
    const float* xg = x + (size_t)bg * 65536 + part * 1024;
    float s = 0.f, ss = 0.f;
#pragma unroll
    for (int r = 0; r < 16; ++r) {
      const float4 v = *(const float4*)(xg + (size_t)r * 4096 + t * 4);
      s += v.x + v.y + v.z + v.w;
      ss += v.x * v.x + v.y * v.y + v.z * v.z + v.w * v.w;
    }
#pragma unroll
    for (int m = 32; m; m >>= 1) { s += __shfl_xor(s, m); ss += __shfl_xor(ss, m); }
    __shared__ float red[8];
    const int wave = t >> 6, lane = t & 63;
    if (lane == 0) { red[wave] = s; red[wave + 4] = ss; }
    __syncthreads();
    if (t == 0) {
      float2 p;
      p.x = red[0] + red[1] + red[2] + red[3];
      p.y = red[4] + red[5] + red[6] + red[7];
      partials[bgq] = p;
    }
    return;
  }
  if (blk >= 4096) {
    lrow[((blk - 4096) << 8) | t] = 0.f;
    return;
  }
  const int m = blk >> 10;
  const float* src = (m == 0) ? wq : (m == 1) ? wk : (m == 2) ? wv : wo;
  const int idx = ((blk & 1023) << 8) | t;
  dst[m * 262144 + idx] = f2bf(src[idx]);
}

__global__ __launch_bounds__(256) void zero_k(float* __restrict__ p, int n) {
  const int i = blockIdx.x * 256 + threadIdx.x;
  if (i < n) p[i] = 0.f;
}

// ---------------- GroupNorm apply + transpose -> h_t [B,N,C] bf16 ----------
__global__ __launch_bounds__(256) void gn_apply(
    const float* __restrict__ x, const float2* __restrict__ partials,
    const float* __restrict__ gw, const float* __restrict__ gb,
    unsigned short* __restrict__ h_t) {
  const int bg = blockIdx.x >> 3, cc = blockIdx.x & 7;
  const int b = bg >> 5, g = bg & 31;
  const int t = threadIdx.x;
  __shared__ float chs[32];
  __shared__ unsigned short tile[16][520];
  if (t < 16) {
    const float2 p0 = partials[bg * 4 + 0], p1 = partials[bg * 4 + 1];
    const float2 p2 = partials[bg * 4 + 2], p3 = partials[bg * 4 + 3];
    const float S = p0.x + p1.x + p2.x + p3.x;
    const float SS = p0.y + p1.y + p2.y + p3.y;
    const float mu = S * (1.f / 65536.f);
    const float rstd = rsqrtf(SS * (1.f / 65536.f) - mu * mu + 1e-5f);
    const float sc = gw[g * 16 + t] * rstd;
    chs[t] = sc;
    chs[16 + t] = gb[g * 16 + t] - mu * sc;
  }
  __syncthreads();
  const float* xg = x + (size_t)bg * 65536 + cc * 512;
#pragma unroll
  for (int rr = 0; rr < 8; ++rr) {
    const int r = rr * 2 + (t >> 7), i = (t & 127) * 4;
    const float4 v = *(const float4*)(xg + (size_t)r * 4096 + i);
    const float sc = chs[r], sh = chs[16 + r];
    ushort4 o;
    o.x = f2bf(v.x * sc + sh); o.y = f2bf(v.y * sc + sh);
    o.z = f2bf(v.z * sc + sh); o.w = f2bf(v.w * sc + sh);
    *(ushort4*)&tile[r][i] = o;
  }
  __syncthreads();
  unsigned short* outp = h_t + ((size_t)b * 4096 + cc * 512) * 512 + g * 16;
#pragma unroll
  for (int rep = 0; rep < 4; ++rep) {
    const int task = rep * 256 + t;
    const int nl = task >> 1, half = (task & 1) * 8;
    ushort4 o0, o1;
    o0.x = tile[half + 0][nl]; o0.y = tile[half + 1][nl];
    o0.z = tile[half + 2][nl]; o0.w = tile[half + 3][nl];
    o1.x = tile[half + 4][nl]; o1.y = tile[half + 5][nl];
    o1.z = tile[half + 6][nl]; o1.w = tile[half + 7][nl];
    *(ushort4*)(outp + (size_t)nl * 512 + half) = o0;
    *(ushort4*)(outp + (size_t)nl * 512 + half + 4) = o1;
  }
}

// ------- reduce 4 fp32 split-K partials, normalize by l[row] -> bf16 --------
__global__ __launch_bounds__(256) void reduce4_k(
    const float* __restrict__ part, const float* __restrict__ l,
    unsigned short* __restrict__ dst) {
  const size_t i = ((size_t)blockIdx.x * 256 + threadIdx.x) * 4;
  f32x4 s0 = *(const f32x4*)(part + i);
  f32x4 s1 = *(const f32x4*)(part + 2097152 + i);
  f32x4 s2 = *(const f32x4*)(part + 4194304 + i);
  f32x4 s3 = *(const f32x4*)(part + 6291456 + i);
  f32x4 s = (s0 + s1) + (s2 + s3);
  const float inv = 1.f / l[i >> 9];
  ushort4 o;
  o.x = f2bf(s[0] * inv); o.y = f2bf(s[1] * inv);
  o.z = f2bf(s[2] * inv); o.w = f2bf(s[3] * inv);
  *(ushort4*)(dst + i) = o;
}

// ---- fused QKV GEMM: 256 threads, 128x128 tiles, grid (12,32,4) = 1536
// ---- blocks (deep grid, 3+/CU -> amortized tail; R8 proved the 768-block
// ---- 512-thread variant loses ~8us to a half-empty second scheduling wave).
// ---- mode = bx>>2 (0=q,1=k,2=v), colv = (bx&3)*128.  W rows bx*128.. =
// ---- concatenated [wq;wk;wv].  Outputs bit-identical to separate launches.
__global__ __launch_bounds__(256) void gemm_qkv(
    const unsigned short* __restrict__ H, const unsigned short* __restrict__ W,
    unsigned short* __restrict__ q_t, unsigned short* __restrict__ k_t,
    unsigned short* __restrict__ v_ct,
    const float* __restrict__ bq, const float* __restrict__ bk,
    const float* __restrict__ bv, float qscale) {
  __shared__ __align__(16) char smem[49152];  // 3 bufs x (A 8KB + B 8KB)
  const int tid = threadIdx.x;
  const int wave = tid >> 6, lane = tid & 63;
  const int l15 = lane & 15, l4 = lane >> 4;
  const int wm = wave >> 1, wn = wave & 1;

  const int bx = blockIdx.x, by = blockIdx.y, bz = blockIdx.z;
  const int mode = bx >> 2;          // 0=q 1=k 2=v
  const int colv = (bx & 3) << 7;    // col within the 512-wide output
  const int row0 = by << 7;
  const unsigned short* A = H + (size_t)bz * 2097152;
  const unsigned short* Bt = W + (size_t)bx * 65536;  // bx*128 rows of 512

  const int ar = tid >> 2;
  const int akc = (tid & 3) ^ ((tid >> 3) & 3);  // row bits 1-2

  auto stage = [&](int kt, int bi) {
    const int kb = kt << 5;
    char* sAl = smem + bi * 16384 + wave * 1024;
    char* sBl = sAl + 8192;
    const unsigned short* gA = A + (size_t)(row0 + ar) * 512 + kb + akc * 8;
    const unsigned short* gB = Bt + (size_t)ar * 512 + kb + akc * 8;
    gload_lds16(gA, sAl);
    gload_lds16(gB, sBl);
    gload_lds16(gA + (size_t)64 * 512, sAl + 4096);
    gload_lds16(gB + (size_t)64 * 512, sBl + 4096);
  };

  f32x4 acc[4][4];
#pragma unroll
  for (int r = 0; r < 4; ++r)
#pragma unroll
    for (int c = 0; c < 4; ++c) acc[r][c] = (f32x4)0.f;

  const int xsw = (l4 ^ ((l15 >> 1) & 3)) << 4;

  auto compute = [&](int bi) {
    const char* pa = smem + bi * 16384 + (wm * 64 + l15) * 64 + xsw;
    const char* pb = smem + bi * 16384 + 8192 + (wn * 64 + l15) * 64 + xsw;
    bf16x8 af[4], bfr[4];
#pragma unroll
    for (int r = 0; r < 4; ++r) af[r] = *(const bf16x8*)(pa + r * 1024);
#pragma unroll
    for (int c = 0; c < 4; ++c) bfr[c] = *(const bf16x8*)(pb + c * 1024);
#pragma unroll
    for (int r = 0; r < 4; ++r)
#pragma unroll
      for (int c = 0; c < 4; ++c)
        acc[r][c] = __builtin_amdgcn_mfma_f32_16x16x32_bf16(af[r], bfr[c], acc[r][c], 0, 0, 0);
  };

  stage(0, 0);
  stage(1, 1);
  int bi = 0;
  for (int kt = 0; kt < 15; ++kt) {  // nk = 16
    asm volatile("s_waitcnt vmcnt(4)" ::: "memory");
    __builtin_amdgcn_s_barrier();
    __builtin_amdgcn_sched_barrier(0);
    if (kt + 2 < 16) stage(kt + 2, (kt + 2) % 3);
    compute(bi);
    bi = (bi == 2) ? 0 : bi + 1;
  }
  asm volatile("s_waitcnt vmcnt(0)" ::: "memory");
  __builtin_amdgcn_s_barrier();
  __builtin_amdgcn_sched_barrier(0);
  compute(bi);

  const float* bias = (mode == 0) ? bq : (mode == 1) ? bk : bv;
  const float scale = (mode == 0) ? qscale : 1.0f;
  __syncthreads();
  if (mode < 2) {
    // q/k: coalesced bf16 [B,N,C] via [128][136] LDS tile
    unsigned short* outp = ((mode == 0) ? q_t : k_t) + (size_t)bz * 2097152;
    unsigned short* tile = (unsigned short*)smem;
#pragma unroll
    for (int c = 0; c < 4; ++c) {
      const int coll = wn * 64 + c * 16 + l15;
      const float badd = bias[colv + coll];
#pragma unroll
      for (int r = 0; r < 4; ++r) {
        const int rowl = wm * 64 + r * 16 + l4 * 4;
#pragma unroll
        for (int j = 0; j < 4; ++j)
          tile[(rowl + j) * 136 + coll] = f2bf((acc[r][c][j] + badd) * scale);
      }
    }
    __syncthreads();
#pragma unroll
    for (int it = 0; it < 8; ++it) {
      const int idx = it * 256 + tid;
      const int rw = idx >> 4, ch = (idx & 15) * 8;
      const uint4 vv = *(const uint4*)&tile[rw * 136 + ch];
      *(uint4*)(outp + (size_t)(row0 + rw) * 512 + colv + ch) = vv;
    }
  } else {
    // v: transposed [B,C,N] via [128][132] LDS tile
    unsigned short* outp = v_ct + (size_t)bz * 2097152;
    unsigned short* tile = (unsigned short*)smem;
#pragma unroll
    for (int c = 0; c < 4; ++c) {
      const int coll = wn * 64 + c * 16 + l15;
      const float badd = bias[colv + coll];
#pragma unroll
      for (int r = 0; r < 4; ++r) {
        const int rowl = wm * 64 + r * 16 + l4 * 4;
#pragma unroll
        for (int j = 0; j < 4; ++j)
          tile[(rowl + j) * 132 + coll] = f2bf(acc[r][c][j] + badd);
      }
    }
    __syncthreads();
#pragma unroll 8
    for (int it = 0; it < 64; ++it) {
      const int idx = it * 256 + tid;
      const int cl = idx >> 7, il = idx & 127;
      outp[(size_t)(colv + cl) * 4096 + row0 + il] = tile[il * 132 + cl];
    }
  }
}

// ---- S-kernel: 256x128 tile, 8 waves, triple-buffered 72KB LDS, 2 blk/CU.
// Depth-2 prefetch, counted vmcnt(3), row-bits-1-2 chunk swizzle (bank-
// uniform b128 reads).  Epilogue: single-pass [256][136] LDS tile, coalesced
// 16B stores + fused per-row sums -> atomicAdd lsum.  z-batched.
// 4x confirmed structural plateau (~88us @33% MfmaUtil) for this K=512
// epilogue-heavy shape; phase-split/persistent/3-blk all measured worse.
__global__ __launch_bounds__(512, 4) void gemm_s256(
    const unsigned short* __restrict__ A, const unsigned short* __restrict__ Bt,
    unsigned short* __restrict__ Out, float* __restrict__ lsum) {
  __shared__ __align__(16) char smem[73728];  // 3 bufs x (A 16KB + B 8KB)
  const int tid = threadIdx.x;
  const int wave = tid >> 6, lane = tid & 63;
  const int l15 = lane & 15, l4 = lane >> 4;
  const int wm = wave >> 1, wn = wave & 1;  // 4 x 2 waves

  const int bz = blockIdx.z;
  A += (size_t)bz * 2097152;
  Bt += (size_t)bz * 2097152;
  Out += (size_t)bz * 16777216;
  lsum += (size_t)bz * 4096;

  // XCD chunking: 8 chunks of 4 row-panels x 16 col-panels (3MB < 4MB L2)
  const int id = blockIdx.y * 32 + blockIdx.x;
  const int xcd = id & 7, j = id >> 3;
  const int by = ((xcd >> 1) << 2) + (j >> 4);
  const int bx = ((xcd & 1) << 4) + (j & 15);
  const int row0 = by << 8, col0 = bx << 7;

  const int ar = tid >> 2;                       // 0..127
  const int akc = (tid & 3) ^ ((tid >> 3) & 3);  // swizzled chunk: row bits 1-2

  auto stage = [&](int kt, int bi) {
    const int kb = kt << 5;
    char* base = smem + bi * 24576;
    const unsigned short* gA = A + (size_t)(row0 + ar) * 512 + kb + akc * 8;
    const unsigned short* gB = Bt + (size_t)(col0 + ar) * 512 + kb + akc * 8;
    gload_lds16(gA, base + wave * 1024);                          // A rows 0-127
    gload_lds16(gA + (size_t)128 * 512, base + 8192 + wave * 1024);  // A 128-255
    gload_lds16(gB, base + 16384 + wave * 1024);                  // B rows 0-127
  };

  f32x4 acc[4][4];
#pragma unroll
  for (int r = 0; r < 4; ++r)
#pragma unroll
    for (int c = 0; c < 4; ++c) acc[r][c] = (f32x4)0.f;

  const int xsw = (l4 ^ ((l15 >> 1) & 3)) << 4;  // matches akc (row bits 1-2)

  auto compute = [&](int bi) {
    const char* pa = smem + bi * 24576 + (wm * 64 + l15) * 64 + xsw;
    const char* pb = smem + bi * 24576 + 16384 + (wn * 64 + l15) * 64 + xsw;
    bf16x8 af[4], bfr[4];
#pragma unroll
    for (int r = 0; r < 4; ++r) af[r] = *(const bf16x8*)(pa + r * 1024);
#pragma unroll
    for (int c = 0; c < 4; ++c) bfr[c] = *(const bf16x8*)(pb + c * 1024);
#pragma unroll
    for (int r = 0; r < 4; ++r)
#pragma unroll
      for (int c = 0; c < 4; ++c)
        acc[r][c] = __builtin_amdgcn_mfma_f32_16x16x32_bf16(af[r], bfr[c], acc[r][c], 0, 0, 0);
  };

  stage(0, 0);
  stage(1, 1);
  int bi = 0;
  for (int kt = 0; kt < 15; ++kt) {  // nk = 512/32 = 16
    asm volatile("s_waitcnt vmcnt(3)" ::: "memory");
    __builtin_amdgcn_s_barrier();
    __builtin_amdgcn_sched_barrier(0);
    if (kt + 2 < 16) stage(kt + 2, (kt + 2) % 3);
    compute(bi);
    bi = (bi == 2) ? 0 : bi + 1;
  }
  asm volatile("s_waitcnt vmcnt(0)" ::: "memory");
  __builtin_amdgcn_s_barrier();
  __builtin_amdgcn_sched_barrier(0);
  compute(bi);

  // epilogue: exp -> bf16 -> single [256][136] LDS pass,
  // coalesced 16B stores, fused per-row sums -> atomicAdd lsum
  __syncthreads();
  unsigned short* tile = (unsigned short*)smem;  // [256][136]
#pragma unroll
  for (int c = 0; c < 4; ++c) {
    const int coll = wn * 64 + c * 16 + l15;
#pragma unroll
    for (int r = 0; r < 4; ++r) {
      const int rowl = wm * 64 + r * 16 + l4 * 4;
#pragma unroll
      for (int j = 0; j < 4; ++j)
        tile[(rowl + j) * 136 + coll] = f2bf(__expf(acc[r][c][j]));
    }
  }
  __syncthreads();
#pragma unroll
  for (int it = 0; it < 8; ++it) {
    const int idx = it * 512 + tid;  // 256 rows x 16 chunks of 8 shorts
    const int rw = idx >> 4, ch = (idx & 15) * 8;
    const uint4 vv = *(const uint4*)&tile[rw * 136 + ch];
    *(uint4*)(Out + (size_t)(row0 + rw) * 4096 + col0 + ch) = vv;
    const unsigned* uu = (const unsigned*)&vv;
    float s = 0.f;
#pragma unroll
    for (int q = 0; q < 4; ++q) {
      union { unsigned u; float f; } w;
      w.u = uu[q] << 16; s += w.f;
      w.u = uu[q] & 0xffff0000u; s += w.f;
    }
    s += __shfl_xor(s, 1); s += __shfl_xor(s, 2);
    s += __shfl_xor(s, 4); s += __shfl_xor(s, 8);
    if ((lane & 15) == 0) atomicAdd(&lsum[row0 + rw], s);
  }
}

// ---- PV GEMM, phase-split schedule (T3+T4+T2+T5) -------------------------
// h2[row,c] = (sum_j P[row,j]*Vt[c,j]) / lrow[row].  256x128 tile, 8 waves,
// BK=64 (nk=64), triple-buffered 48KB tiles (144KB LDS, 1 blk/CU).
// Deep K-loop amortizes the 1-blk occupancy; counted vmcnt(6), XOR-8 swizzle
// via pre-swizzled global source, setprio around MFMA clusters.  (R11: the
// flash-fused variant lost 80us to 16-way-split V loads -- V staging via
// gload_lds here is the whole reason this decomposition wins.)
__global__ __launch_bounds__(512, 2) void gemm_pv(
    const unsigned short* __restrict__ P, const unsigned short* __restrict__ Vt,
    unsigned short* __restrict__ Out, const float* __restrict__ lrow) {
  __shared__ __align__(16) char smem[147456];  // 3 x (A 32KB + B 16KB)
  const int tid = threadIdx.x;
  const int wave = tid >> 6, lane = tid & 63;
  const int l15 = lane & 15, l4 = lane >> 4;
  const int wm = wave >> 1, wn = wave & 1;  // 4M x 2N waves

  // grid (4,16,4) = 256 blocks; linear id mod 8 = XCD (round-robin)
  const int L = blockIdx.x + ((blockIdx.y + (blockIdx.z << 4)) << 2);
  const int xcd = L & 7, j = L >> 3;
  const int panel = xcd * 8 + (j >> 2);  // 8 (by,bz) panels per XCD
  const int bx = j & 3, by = panel & 15, bz = panel >> 4;
  const int row0 = by << 8, col0 = bx << 7;
  P += (size_t)bz * 16777216;
  Vt += (size_t)bz * 2097152;
  Out += (size_t)bz * 2097152;
  lrow += bz * 4096;

  // staging: one pass = 512 threads x 16B = 64 rows x 128B (linear LDS dest)
  const int sr = tid >> 3;               // row within pass
  const int sc8 = (tid & 7) ^ (sr & 7);  // pre-swizzled source chunk (XOR-8)
  const unsigned short* gA = P + (size_t)(row0 + sr) * 4096 + sc8 * 8;
  const unsigned short* gB = Vt + (size_t)(col0 + sr) * 4096 + sc8 * 8;

  auto stA = [&](int kt, int bi, int p) {  // A: 256x64 bf16 = 4 passes
    gload_lds16(gA + (size_t)(p << 6) * 4096 + (kt << 6),
                smem + bi * 49152 + p * 8192 + wave * 1024);
  };
  auto stB = [&](int kt, int bi, int p) {  // B: 128x64 bf16 = 2 passes
    gload_lds16(gB + (size_t)(p << 6) * 4096 + (kt << 6),
                smem + bi * 49152 + 32768 + p * 8192 + wave * 1024);
  };

  f32x4 acc[4][4];
#pragma unroll
  for (int r = 0; r < 4; ++r)
#pragma unroll
    for (int c = 0; c < 4; ++c) acc[r][c] = (f32x4)0.f;

  // read-side swizzled 16B slots: slot = (kk*4 + l4) ^ (row & 7), row&7 = l15&7
  const int sw0 = (l4 ^ (l15 & 7)) << 4;
  const int sw1 = ((4 + l4) ^ (l15 & 7)) << 4;
  const int arow = (wm * 64 + l15) << 7;  // 128B row stride
  const int brow = (wn * 64 + l15) << 7;

  bf16x8 bfr[4][2];

  // prologue: 2 tiles in flight (12 loads), gate tile 0 with vmcnt(6)
  stA(0, 0, 0); stA(0, 0, 1); stA(0, 0, 2); stA(0, 0, 3);
  stB(0, 0, 0); stB(0, 0, 1);
  stA(1, 1, 0); stA(1, 1, 1); stA(1, 1, 2); stA(1, 1, 3);
  stB(1, 1, 0); stB(1, 1, 1);
  asm volatile("s_waitcnt vmcnt(6)" ::: "memory");
  __builtin_amdgcn_s_barrier();
  __builtin_amdgcn_sched_barrier(0);

  int bi = 0;
#pragma unroll 1
  for (int kt = 0; kt < 64; ++kt) {  // nk = 4096/64
    const char* bufA = smem + bi * 49152;
    const char* bufB = bufA + 32768;
    const int pb = (bi + 2) % 3;
    const bool pre = (kt + 2 < 64);
    bf16x8 a0, a1;
    // ---- phase 0: r=0 (+ all B fragments), stage A passes 0-1 ----
    a0 = *(const bf16x8*)(bufA + arow + sw0);
    a1 = *(const bf16x8*)(bufA + arow + sw1);
#pragma unroll
    for (int c = 0; c < 4; ++c) {
      bfr[c][0] = *(const bf16x8*)(bufB + brow + c * 2048 + sw0);
      bfr[c][1] = *(const bf16x8*)(bufB + brow + c * 2048 + sw1);
    }
    if (pre) { stA(kt + 2, pb, 0); stA(kt + 2, pb, 1); }
    __builtin_amdgcn_s_barrier();
    asm volatile("s_waitcnt lgkmcnt(0)" ::: "memory");
    __builtin_amdgcn_sched_barrier(0);
    __builtin_amdgcn_s_setprio(1);
#pragma unroll
    for (int c = 0; c < 4; ++c) {
      acc[0][c] = __builtin_amdgcn_mfma_f32_16x16x32_bf16(a0, bfr[c][0], acc[0][c], 0, 0, 0);
      acc[0][c] = __builtin_amdgcn_mfma_f32_16x16x32_bf16(a1, bfr[c][1], acc[0][c], 0, 0, 0);
    }
    __builtin_amdgcn_s_setprio(0);
    __builtin_amdgcn_s_barrier();
    // ---- phase 1: r=1, stage A passes 2-3 ----
    a0 = *(const bf16x8*)(bufA + arow + 2048 + sw0);
    a1 = *(const bf16x8*)(bufA + arow + 2048 + sw1);
    if (pre) { stA(kt + 2, pb, 2); stA(kt + 2, pb, 3); }
    __builtin_amdgcn_s_barrier();
    asm volatile("s_waitcnt lgkmcnt(0)" ::: "memory");
    __builtin_amdgcn_sched_barrier(0);
    __builtin_amdgcn_s_setprio(1);
#pragma unroll
    for (int c = 0; c < 4; ++c) {
      acc[1][c] = __builtin_amdgcn_mfma_f32_16x16x32_bf16(a0, bfr[c][0], acc[1][c], 0, 0, 0);
      acc[1][c] = __builtin_amdgcn_mfma_f32_16x16x32_bf16(a1, bfr[c][1], acc[1][c], 0, 0, 0);
    }
    __builtin_amdgcn_s_setprio(0);
    __builtin_amdgcn_s_barrier();
    // ---- phase 2: r=2, stage B passes 0-1 ----
    a0 = *(const bf16x8*)(bufA + arow + 4096 + sw0);
    a1 = *(const bf16x8*)(bufA + arow + 4096 + sw1);
    if (pre) { stB(kt + 2, pb, 0); stB(kt + 2, pb, 1); }
    __builtin_amdgcn_s_barrier();
    asm volatile("s_waitcnt lgkmcnt(0)" ::: "memory");
    __builtin_amdgcn_sched_barrier(0);
    __builtin_amdgcn_s_setprio(1);
#pragma unroll
    for (int c = 0; c < 4; ++c) {
      acc[2][c] = __builtin_amdgcn_mfma_f32_16x16x32_bf16(a0, bfr[c][0], acc[2][c], 0, 0, 0);
      acc[2][c] = __builtin_amdgcn_mfma_f32_16x16x32_bf16(a1, bfr[c][1], acc[2][c], 0, 0, 0);
    }
    __builtin_amdgcn_s_setprio(0);
    __builtin_amdgcn_s_barrier();
    // ---- phase 3: r=3, counted vmcnt gate for next tile (never 0 mid-loop)
    a0 = *(const bf16x8*)(bufA + arow + 6144 + sw0);
    a1 = *(const bf16x8*)(bufA + arow + 6144 + sw1);
    __builtin_amdgcn_s_barrier();
    asm volatile("s_waitcnt lgkmcnt(0)" ::: "memory");
    __builtin_amdgcn_sched_barrier(0);
    __builtin_amdgcn_s_setprio(1);
#pragma unroll
    for (int c = 0; c < 4; ++c) {
      acc[3][c] = __builtin_amdgcn_mfma_f32_16x16x32_bf16(a0, bfr[c][0], acc[3][c], 0, 0, 0);
      acc[3][c] = __builtin_amdgcn_mfma_f32_16x16x32_bf16(a1, bfr[c][1], acc[3][c], 0, 0, 0);
    }
    __builtin_amdgcn_s_setprio(0);
    if (pre) asm volatile("s_waitcnt vmcnt(6)" ::: "memory");
    else     asm volatile("s_waitcnt vmcnt(0)" ::: "memory");
    __builtin_amdgcn_s_barrier();
    __builtin_amdgcn_sched_barrier(0);
    bi = (bi == 2) ? 0 : bi + 1;
  }

  // epilogue: row-normalize -> bf16 -> LDS tile -> coalesced 16B stores
  __syncthreads();
  unsigned short* tile = (unsigned short*)smem;  // [256][136]
#pragma unroll
  for (int c = 0; c < 4; ++c) {
    const int coll = wn * 64 + c * 16 + l15;
#pragma unroll
    for (int r = 0; r < 4; ++r) {
      const int rowl = wm * 64 + r * 16 + l4 * 4;
#pragma unroll
      for (int j = 0; j < 4; ++j) {
        const float v = acc[r][c][j] * (1.0f / lrow[row0 + rowl + j]);
        tile[(rowl + j) * 136 + coll] = f2bf(v);
      }
    }
  }
  __syncthreads();
#pragma unroll
  for (int it = 0; it < 8; ++it) {
    const int idx = it * 512 + tid;  // 256 rows x 16 chunks of 8 shorts
    const int rw = idx >> 4, ch = (idx & 15) * 8;
    const uint4 vv = *(const uint4*)&tile[rw * 136 + ch];
    *(uint4*)(Out + (size_t)(row0 + rw) * 512 + col0 + ch) = vv;
  }
}

// ---------------- GEMM: C[M,N] = A[M,K] * Bt[N,K]^T  (bf16 in, fp32 acc) -------
// Triple-buffered LDS, prefetch depth 2, counted s_waitcnt vmcnt(4).
// SWZ: 0 none, 1 XCD-chunked, 2 XCD panel-grouping.  COAL: LDS-staged
// row-coalesced stores.  BIAS_MODE: 0 none, 1 per-col, 2 per-row,
// 3 row-normalize.  Chunk swizzle uses row bits 1-2 (bank-uniform).
template <bool OUT_BF16, int BIAS_MODE, bool RESID, bool TRANS_OUT, int SWZ,
          bool COAL>
__global__ __launch_bounds__(256) void gemm_bt(
    const unsigned short* __restrict__ A, long long sA, int lda,
    const unsigned short* __restrict__ Bt, long long sB, int ldb,
    void* __restrict__ OutV, long long sO, int ldo,
    const float* __restrict__ bias,
    const float* __restrict__ resid, long long sR,
    int K, float scale) {
  __shared__ __align__(16) char smem[49152];  // 3 bufs x (A 8KB + B 8KB)
  const int tid = threadIdx.x;
  const int wave = tid >> 6, lane = tid & 63;
  const int l15 = lane & 15, l4 = lane >> 4;
  const int wm = wave >> 1, wn = wave & 1;

  int bx = blockIdx.x, by = blockIdx.y, bz = blockIdx.z;
  if constexpr (SWZ == 1) {
    const int id = by * 32 + bx;
    const int xcd = id & 7, j = id >> 3;
    by = ((xcd >> 1) << 3) + (j >> 4);
    bx = ((xcd & 1) << 4) + (j & 15);
  } else if constexpr (SWZ == 2) {
    const int L = bx + ((by + (bz << 5)) << 2);
    const int xcd = L & 7, j = L >> 3;
    const int pair = xcd * 16 + (j >> 2);
    bx = j & 3;
    by = pair & 31;
    bz = pair >> 5;
  }
  const int row0 = by << 7, col0 = bx << 7;
  A += (size_t)bz * sA;
  Bt += (size_t)bz * sB;
  if (RESID) resid += (size_t)bz * sR;
  if constexpr (BIAS_MODE == 3) bias += (size_t)bz * sR;
  char* outB = (char*)OutV + (size_t)bz * sO * (OUT_BF16 ? 2 : 4);

  const int ar = tid >> 2;
  const int akc = (tid & 3) ^ ((tid >> 3) & 3);  // row bits 1-2

  auto stage = [&](int kt, int bi) {
    const int kb = kt << 5;
    char* sAl = smem + bi * 16384 + wave * 1024;
    char* sBl = sAl + 8192;
    const unsigned short* gA = A + (size_t)(row0 + ar) * lda + kb + akc * 8;
    const unsigned short* gB = Bt + (size_t)(col0 + ar) * ldb + kb + akc * 8;
    gload_lds16(gA, sAl);
    gload_lds16(gB, sBl);
    gload_lds16(gA + (size_t)64 * lda, sAl + 4096);
    gload_lds16(gB + (size_t)64 * ldb, sBl + 4096);
  };

  f32x4 acc[4][4];
#pragma unroll
  for (int r = 0; r < 4; ++r)
#pragma unroll
    for (int c = 0; c < 4; ++c) acc[r][c] = (f32x4)0.f;

  const int nk = K >> 5;
  const int xsw = (l4 ^ ((l15 >> 1) & 3)) << 4;  // matches akc

  auto compute = [&](int bi) {
    const char* pa = smem + bi * 16384 + (wm * 64 + l15) * 64 + xsw;
    const char* pb = smem + bi * 16384 + 8192 + (wn * 64 + l15) * 64 + xsw;
    bf16x8 af[4], bfr[4];
#pragma unroll
    for (int r = 0; r < 4; ++r) af[r] = *(const bf16x8*)(pa + r * 1024);
#pragma unroll
    for (int c = 0; c < 4; ++c) bfr[c] = *(const bf16x8*)(pb + c * 1024);
#pragma unroll
    for (int r = 0; r < 4; ++r)
#pragma unroll
      for (int c = 0; c < 4; ++c)
        acc[r][c] = __builtin_amdgcn_mfma_f32_16x16x32_bf16(af[r], bfr[c], acc[r][c], 0, 0, 0);
  };

  stage(0, 0);
  stage(1, 1);
  int bi = 0;
  for (int kt = 0; kt < nk - 1; ++kt) {
    asm volatile("s_waitcnt vmcnt(4)" ::: "memory");
    __builtin_amdgcn_s_barrier();
    __builtin_amdgcn_sched_barrier(0);
    if (kt + 2 < nk) stage(kt + 2, (kt + 2) % 3);
    compute(bi);
    bi = (bi == 2) ? 0 : bi + 1;
  }
  asm volatile("s_waitcnt vmcnt(0)" ::: "memory");
  __builtin_amdgcn_s_barrier();
  __builtin_amdgcn_sched_barrier(0);
  compute(bi);

  if constexpr (COAL && !TRANS_OUT) {
    __syncthreads();
    if constexpr (OUT_BF16) {
      unsigned short* tile = (unsigned short*)smem;  // [128][136]
#pragma unroll
      for (int c = 0; c < 4; ++c) {
        const int coll = wn * 64 + c * 16 + l15;
        float badd = 0.f;
        if constexpr (BIAS_MODE == 1) badd = bias[col0 + coll];
#pragma unroll
        for (int r = 0; r < 4; ++r) {
          const int rowl = wm * 64 + r * 16 + l4 * 4;
#pragma unroll
          for (int j = 0; j < 4; ++j) {
            float v;
            if constexpr (BIAS_MODE == 3)
              v = acc[r][c][j] * (1.0f / bias[row0 + rowl + j]);
            else
              v = (acc[r][c][j] + badd) * scale;
            tile[(rowl + j) * 136 + coll] = f2bf(v);
          }
        }
      }
      __syncthreads();
      unsigned short* outp = (unsigned short*)outB;
#pragma unroll
      for (int it = 0; it < 8; ++it) {
        const int idx = it * 256 + tid;  // 128 rows x 16 chunks of 8 shorts
        const int rw = idx >> 4, ch = (idx & 15) * 8;
        const uint4 vv = *(const uint4*)&tile[rw * 136 + ch];
        *(uint4*)(outp + (size_t)(row0 + rw) * ldo + col0 + ch) = vv;
      }
    } else {
      float* tile = (float*)smem;  // [64][132]
#pragma unroll
      for (int p = 0; p < 2; ++p) {
        if (wm == p) {
#pragma unroll
          for (int c = 0; c < 4; ++c) {
            const int coll = wn * 64 + c * 16 + l15;
            float badd = 0.f;
            if constexpr (BIAS_MODE == 1) badd = bias[col0 + coll];
#pragma unroll
            for (int r = 0; r < 4; ++r) {
              const int rowl = r * 16 + l4 * 4;
#pragma unroll
              for (int j = 0; j < 4; ++j) {
                float v = acc[r][c][j] + badd;
                if constexpr (BIAS_MODE == 2) v += bias[row0 + p * 64 + rowl + j];
                tile[(rowl + j) * 132 + coll] = v * scale;
              }
            }
          }
        }
        __syncthreads();
        float* outp = (float*)outB;
#pragma unroll
        for (int it = 0; it < 8; ++it) {
          const int idx = it * 256 + tid;  // 64 rows x 32 chunks of 4 floats
          const int rw = idx >> 5, ch = (idx & 31) * 4;
          const int rowg = row0 + p * 64 + rw;
          f32x4 v = *(const f32x4*)&tile[rw * 132 + ch];
          if constexpr (RESID) {
            const float* rp = resid + (size_t)rowg * ldo + col0 + ch;
            v[0] += rp[0]; v[1] += rp[1]; v[2] += rp[2]; v[3] += rp[3];
          }
          *(f32x4*)(outp + (size_t)rowg * ldo + col0 + ch) = v;
        }
        __syncthreads();
      }
    }
  } else if constexpr (!TRANS_OUT) {
#pragma unroll
    for (int c = 0; c < 4; ++c) {
      const int colg = col0 + wn * 64 + c * 16 + l15;
      float badd = 0.f;
      if constexpr (BIAS_MODE == 1) badd = bias[colg];
#pragma unroll
      for (int r = 0; r < 4; ++r) {
        const int rowg = row0 + wm * 64 + r * 16 + l4 * 4;
#pragma unroll
        for (int j = 0; j < 4; ++j) {
          float v = acc[r][c][j] + badd;
          if constexpr (BIAS_MODE == 2) v += bias[rowg + j];
          v *= scale;
          if constexpr (RESID) v += resid[(size_t)(rowg + j) * ldo + colg];
          if constexpr (OUT_BF16)
            ((unsigned short*)outB)[(size_t)(rowg + j) * ldo + colg] = f2bf(v);
          else
            ((float*)outB)[(size_t)(rowg + j) * ldo + colg] = v;
        }
      }
    }
  } else {
    __syncthreads();
    unsigned short* tile = (unsigned short*)smem;  // [128][132]
#pragma unroll
    for (int c = 0; c < 4; ++c) {
      const int coll = wn * 64 + c * 16 + l15;
      float badd = 0.f;
      if constexpr (BIAS_MODE == 1) badd = bias[col0 + coll];
#pragma unroll
      for (int r = 0; r < 4; ++r) {
        const int rowl = wm * 64 + r * 16 + l4 * 4;
#pragma unroll
        for (int j = 0; j < 4; ++j)
          tile[(rowl + j) * 132 + coll] = f2bf((acc[r][c][j] + badd) * scale);
      }
    }
    __syncthreads();
    unsigned short* outp = (unsigned short*)outB;
#pragma unroll 8
    for (int it = 0; it < 64; ++it) {
      const int idx = it * 256 + tid;
      const int cl = idx >> 7, il = idx & 127;
      outp[(size_t)(col0 + cl) * ldo + row0 + il] = tile[il * 132 + cl];
    }
  }
}

extern "C" void kernel_launch(void* const* d_in, const int* in_sizes, int n_in,
                              void* d_out, int out_size, void* d_ws, size_t ws_size,
                              hipStream_t stream) {
  const float* x   = (const float*)d_in[0];
  const float* gnw = (const float*)d_in[1];
  const float* gnb = (const float*)d_in[2];
  const float* wq  = (const float*)d_in[3];
  const float* bq  = (const float*)d_in[4];
  const float* wk  = (const float*)d_in[5];
  const float* bk  = (const float*)d_in[6];
  const float* wv  = (const float*)d_in[7];
  const float* bv  = (const float*)d_in[8];
  const float* wo  = (const float*)d_in[9];
  const float* bo  = (const float*)d_in[10];
  float* out = (float*)d_out;
  char* ws = (char*)d_ws;

  const size_t MB = 1u << 20;
  float2*         gnp  = (float2*)ws;                          // 4 KB partials
  float*          lrow = (float*)(ws + 64 * 1024);             // 64 KB row sums (4 batches)
  unsigned short* wbf  = (unsigned short*)(ws + 1 * MB);       // 2 MB
  unsigned short* h_t  = (unsigned short*)(ws + 3 * MB);       // 16 MB [B,N,C]
  unsigned short* q_t  = (unsigned short*)(ws + 19 * MB);      // 16 MB
  unsigned short* k_t  = (unsigned short*)(ws + 35 * MB);      // 16 MB
  unsigned short* v_ct = (unsigned short*)(ws + 51 * MB);      // 16 MB [B,C,N]
  unsigned short* h2_t = (unsigned short*)(ws + 67 * MB);      // 16 MB (ends 83)
  unsigned short* Pbuf = (unsigned short*)(ws + 83 * MB);      // up to 128 MB expP
  float*          part = (float*)(ws + 115 * MB);              // 32 MB (fallback only)

  const long long BS = 2097152;    // 4096*512 per-batch stride
  const float qscale = 0.044194173824159216f;  // 512^-0.5
  const bool batched = ws_size >= 212 * MB;

  // weight convert + lrow zero + gn_stats in ONE launch (all input-only)
  convert_w<<<dim3(4672), dim3(256), 0, stream>>>(wq, wk, wv, wo, wbf, lrow, x, gnp);
  gn_apply<<<dim3(1024), dim3(256), 0, stream>>>(x, gnp, gnw, gnb, h_t);

  // fused q/k/v: one 256-thread launch, deep grid (1536 blocks, 3+/CU)
  gemm_qkv<<<dim3(12, 32, 4), dim3(256), 0, stream>>>(
      h_t, wbf, q_t, k_t, v_ct, bq, bk, bv, qscale);

  if (batched) {
    // all 4 batches in one z-batched launch
    gemm_s256<<<dim3(32, 16, 4), dim3(512), 0, stream>>>(q_t, k_t, Pbuf, lrow);
    // h2 = (expP @ v_ct^T) / l[row], phase-split 256x128 schedule
    gemm_pv<<<dim3(4, 16, 4), dim3(512), 0, stream>>>(Pbuf, v_ct, h2_t, lrow);
  } else {
    for (int b = 0; b < 4; ++b) {
      zero_k<<<dim3(16), dim3(256), 0, stream>>>(lrow, 4096);
      gemm_s256<<<dim3(32, 16, 1), dim3(512), 0, stream>>>(
          q_t + (size_t)b * BS, k_t + (size_t)b * BS, Pbuf, lrow);
      gemm_bt<false, 0, false, false, 0, true><<<dim3(4, 32, 4), 256, 0, stream>>>(
          Pbuf, 1024, 4096, v_ct + (size_t)b * BS, 1024, 4096,
          part, 2097152, 512, nullptr, nullptr, 0, 1024, 1.0f);
      reduce4_k<<<dim3(2048), dim3(256), 0, stream>>>(part, lrow, h2_t + (size_t)b * BS);
    }
  }

  // out[b,o,i] = x[b,o,i] + bo[o] + sum_c wo[o,c] h2[b,i,c]
  gemm_bt<false, 2, true, false, 0, true><<<dim3(32, 4, 4), 256, 0, stream>>>(
      wbf + 786432, 0, 512, h2_t, BS, 512, out, BS, 4096, bo, x, BS, 512, 1.0f);
}